// Round 2
// baseline (296.209 us; speedup 1.0000x reference)
//
#include <hip/hip_runtime.h>

#define NTOK 32768

typedef __attribute__((ext_vector_type(8))) short  bf16x8;
typedef __attribute__((ext_vector_type(8))) unsigned short u16x8;
typedef __attribute__((ext_vector_type(4))) float  f32x4;

__device__ __forceinline__ unsigned short f32_to_bf16(float f) {
    unsigned int u = __float_as_uint(f);
    u += 0x7FFFu + ((u >> 16) & 1u);          // round-to-nearest-even
    return (unsigned short)(u >> 16);
}
__device__ __forceinline__ float bf16_to_f32(unsigned short h) {
    return __uint_as_float(((unsigned int)h) << 16);
}

// ---------------------------------------------------------------------------
// B-stationary MFMA GEMM: C[M,NTOK] = A[M,256] * B[256,NTOK].
// One block per 128-col strip (x) per batch (y): B tile [256k][128n] staged
// to LDS bf16 transposed (Bs[n][k], 16B-granule XOR swizzle). 512 threads =
// 8 waves (4m x 2n): wave = 32 rows x 64 cols = 2mt x 4nt tiles -> acc is
// only 8 f32x4/wave, so 2 blocks/CU = 16 waves/CU (launch_bounds(512,4)).
// MFMA operands are SWAPPED (bf as A-operand): D lane layout becomes
// row=lane&15 (fixed), cols quad*4+r (consecutive) -> vectorized 8B/16B
// stores. A fragments gathered from global (L2-resident), no K-loop barriers.
// QSOFT: chunks 0,1 are q rows; each wave owns exactly one head's 32 rows ->
// softmax = mt-pair in-register + shfl_xor 1/2/4/8 over the m16 lanes.
// ---------------------------------------------------------------------------
template <typename BT, typename CT, int MCHUNKS, bool QSOFT>
__global__ __launch_bounds__(512, 4) void gemm_bstat(
    const unsigned short* __restrict__ A, const BT* __restrict__ B,
    CT* __restrict__ C, long sA, long sB, long sC)
{
    const int bz = blockIdx.y;
    A += (long)bz * sA; B += (long)bz * sB; C += (long)bz * sC;
    const int col0 = blockIdx.x * 128;

    __shared__ unsigned short Bs[128 * 256];   // 64 KB

    const int t = threadIdx.x;
    const int wave = t >> 6, lane = t & 63;
    const int wm = wave >> 1, wn = wave & 1;   // 4 m-groups x 2 n-groups
    const int m16 = lane & 15, quad = lane >> 4;

    // ---- stage B tile once: [256k][128n] fp32/bf16 -> Bs[n][256k] bf16
    {
        const int n = t & 127;                  // column
        const int kg0 = (t >> 7) * 8;           // 4 k-quarters, 8 granules each
        const int key = n & 7;
        const BT* bcol = B + col0 + n;
        #pragma unroll
        for (int g = 0; g < 8; ++g) {
            const int kg = kg0 + g;             // 16B granule index along k (0..31)
            unsigned short tmp[8];
            #pragma unroll
            for (int i = 0; i < 8; ++i) {
                BT v = bcol[(size_t)(kg * 8 + i) * NTOK];
                if constexpr (sizeof(BT) == 4) tmp[i] = f32_to_bf16((float)v);
                else                           tmp[i] = (unsigned short)v;
            }
            *(u16x8*)&Bs[n * 256 + ((kg ^ key) * 8)] = *(const u16x8*)tmp;
        }
    }
    __syncthreads();   // the only barrier

    const int swk = m16 & 7;

    for (int mc = 0; mc < MCHUNKS; ++mc) {
        const int m0 = mc * 128;
        f32x4 acc[2][4] = {};

        // lane-base pointer into A for this chunk's fragments (32 rows/wave)
        const unsigned short* Abase = A + (size_t)(m0 + wm * 32 + m16) * 256 + quad * 8;

        #pragma unroll
        for (int kk = 0; kk < 8; ++kk) {
            bf16x8 bf[4];
            #pragma unroll
            for (int nt = 0; nt < 4; ++nt) {
                const int col = wn * 64 + nt * 16 + m16;
                bf[nt] = *(const bf16x8*)&Bs[col * 256 + (((kk * 4 + quad) ^ swk) * 8)];
            }
            #pragma unroll
            for (int mt = 0; mt < 2; ++mt) {
                const bf16x8 af = *(const bf16x8*)&Abase[(size_t)mt * 16 * 256 + kk * 32];
                #pragma unroll
                for (int nt = 0; nt < 4; ++nt)
                    acc[mt][nt] = __builtin_amdgcn_mfma_f32_16x16x32_bf16(
                        bf[nt], af, acc[mt][nt], 0, 0, 0);   // SWAPPED operands
            }
        }

        // ---- fused q softmax: wave owns one head's 32 rows (mt pair + m16 lanes)
        if (QSOFT && m0 < 256) {
            #pragma unroll
            for (int nt = 0; nt < 4; ++nt) {
                #pragma unroll
                for (int r = 0; r < 4; ++r) {
                    float mx = fmaxf(acc[0][nt][r], acc[1][nt][r]);
                    mx = fmaxf(mx, __shfl_xor(mx, 1, 64));
                    mx = fmaxf(mx, __shfl_xor(mx, 2, 64));
                    mx = fmaxf(mx, __shfl_xor(mx, 4, 64));
                    mx = fmaxf(mx, __shfl_xor(mx, 8, 64));
                    const float e0 = __expf(acc[0][nt][r] - mx);
                    const float e1 = __expf(acc[1][nt][r] - mx);
                    float s = e0 + e1;
                    s += __shfl_xor(s, 1, 64);
                    s += __shfl_xor(s, 2, 64);
                    s += __shfl_xor(s, 4, 64);
                    s += __shfl_xor(s, 8, 64);
                    const float inv = 1.0f / s;
                    acc[0][nt][r] = e0 * inv;
                    acc[1][nt][r] = e1 * inv;
                }
            }
        }

        // ---- store: lane holds row = mt*16+m16 (fixed), 4 consecutive cols
        #pragma unroll
        for (int mt = 0; mt < 2; ++mt) {
            const int row = m0 + wm * 32 + mt * 16 + m16;
            #pragma unroll
            for (int nt = 0; nt < 4; ++nt) {
                const int col = col0 + wn * 64 + nt * 16 + quad * 4;
                if constexpr (sizeof(CT) == 4) {
                    *(float4*)&C[(size_t)row * NTOK + col] =
                        *(const float4*)&acc[mt][nt];
                } else {
                    ushort4 o;
                    o.x = f32_to_bf16(acc[mt][nt][0]);
                    o.y = f32_to_bf16(acc[mt][nt][1]);
                    o.z = f32_to_bf16(acc[mt][nt][2]);
                    o.w = f32_to_bf16(acc[mt][nt][3]);
                    *(ushort4*)&C[(size_t)row * NTOK + col] = o;
                }
            }
        }
    }
}

// ---------------------------------------------------------------------------
// fp32 -> bf16 cast (vectorized)
// ---------------------------------------------------------------------------
__global__ __launch_bounds__(256) void cast_bf16_kernel(
    const float* __restrict__ src, unsigned short* __restrict__ dst, int n4)
{
    const int i = blockIdx.x * 256 + threadIdx.x;
    if (i < n4) {
        float4 v = ((const float4*)src)[i];
        ushort4 o;
        o.x = f32_to_bf16(v.x); o.y = f32_to_bf16(v.y);
        o.z = f32_to_bf16(v.z); o.w = f32_to_bf16(v.w);
        ((ushort4*)dst)[i] = o;
    }
}

// ---------------------------------------------------------------------------
// MFMA-based context: num[b,h,d,e] = sum_n exp(k[d,n]) * v[e,n];
// den[b,h,d] = sum_n exp(k[d,n]). Fragments gathered straight from global
// (tokens contiguous = MFMA K-dim -> 16B/lane loads). No LDS, no barriers.
// ---------------------------------------------------------------------------
#define CCHUNK 256
__global__ __launch_bounds__(512) void ctx_mfma_kernel(
    const unsigned short* __restrict__ qkv,
    float* __restrict__ num, float* __restrict__ den)
{
    const int b = blockIdx.y;
    const int n0 = blockIdx.x * CCHUNK;
    const int h = threadIdx.x >> 6;           // wave id == head id
    const int lane = threadIdx.x & 63;
    const int m16 = lane & 15, quad = lane >> 4;

    const unsigned short* kb =
        qkv + ((long)b * 768 + 256 + h * 32 + m16) * (long)NTOK + n0 + quad * 8;
    const unsigned short* vb =
        qkv + ((long)b * 768 + 512 + h * 32 + m16) * (long)NTOK + n0 + quad * 8;

    f32x4 acc[2][2] = {};       // [dtile][etile]
    float dp[2] = {0.f, 0.f};   // den partials

    #pragma unroll
    for (int n = 0; n < CCHUNK; n += 32) {
        bf16x8 af[2], bfv[2];
        #pragma unroll
        for (int dt = 0; dt < 2; ++dt) {
            const u16x8 kr = *(const u16x8*)(kb + (size_t)dt * 16 * NTOK + n);
            unsigned short tmp[8];
            #pragma unroll
            for (int i = 0; i < 8; ++i) {
                const float e = __expf(bf16_to_f32(kr[i]));
                const unsigned short eb = f32_to_bf16(e);
                tmp[i] = eb;
                dp[dt] += bf16_to_f32(eb);
            }
            af[dt] = *(const bf16x8*)tmp;
        }
        #pragma unroll
        for (int et = 0; et < 2; ++et)
            bfv[et] = *(const bf16x8*)(vb + (size_t)et * 16 * NTOK + n);
        #pragma unroll
        for (int dt = 0; dt < 2; ++dt)
            #pragma unroll
            for (int et = 0; et < 2; ++et)
                acc[dt][et] = __builtin_amdgcn_mfma_f32_16x16x32_bf16(
                    af[dt], bfv[et], acc[dt][et], 0, 0, 0);
    }

    float* nbase = num + ((long)(b * 8 + h) * 32) * 32;
    #pragma unroll
    for (int dt = 0; dt < 2; ++dt)
        #pragma unroll
        for (int et = 0; et < 2; ++et)
            #pragma unroll
            for (int r = 0; r < 4; ++r)
                atomicAdd(&nbase[(dt * 16 + quad * 4 + r) * 32 + et * 16 + m16],
                          acc[dt][et][r]);

    #pragma unroll
    for (int dt = 0; dt < 2; ++dt) {
        float s = dp[dt];
        s += __shfl_xor(s, 16, 64);
        s += __shfl_xor(s, 32, 64);
        if (quad == 0)
            atomicAdd(&den[b * 256 + h * 32 + dt * 16 + m16], s);
    }
}

// ---------------------------------------------------------------------------
// W2[b][o][h*32+d] = (sum_e w_out[o,h*32+e] * num[b,h,d,e]) / den[b,h*32+d]
// ---------------------------------------------------------------------------
__global__ __launch_bounds__(256) void combine_kernel(
    const float* __restrict__ w_out, const float* __restrict__ num,
    const float* __restrict__ den, unsigned short* __restrict__ W2)
{
    const int tid = blockIdx.x * 256 + threadIdx.x;   // 2*256*256 total
    const int b = tid >> 16;
    const int rem = tid & 65535;
    const int o = rem >> 8;
    const int i = rem & 255;
    const int h = i >> 5, d = i & 31;
    const float* wrow = w_out + o * 256 + h * 32;
    const float* nrow = num + (((long)(b * 8 + h) * 32 + d) << 5);
    float s = 0.f;
    #pragma unroll
    for (int e = 0; e < 32; ++e) s += wrow[e] * nrow[e];
    W2[tid] = f32_to_bf16(s / den[b * 256 + h * 32 + d]);
}

// ---------------------------------------------------------------------------
extern "C" void kernel_launch(void* const* d_in, const int* in_sizes, int n_in,
                              void* d_out, int out_size, void* d_ws, size_t ws_size,
                              hipStream_t stream)
{
    const float* x     = (const float*)d_in[0];   // [2,256,32768]
    const float* w_qkv = (const float*)d_in[1];   // [768,256]
    const float* w_out = (const float*)d_in[2];   // [256,256]
    float* out = (float*)d_out;                   // [2,256,32768]

    // workspace layout
    unsigned short* qkv_bf = (unsigned short*)d_ws;           // 2*768*32768 bf16
    const long qkv_elems = 2L * 768 * NTOK;
    unsigned short* wqkv_bf = qkv_bf + qkv_elems;             // 768*256 bf16
    unsigned short* W2 = wqkv_bf + 768 * 256;                 // 2*256*256 bf16
    float* num  = (float*)(W2 + 2 * 256 * 256);               // 16384
    float* den  = num + 16384;                                // 512

    hipMemsetAsync(num, 0, (16384 + 512) * sizeof(float), stream);

    // 0) cast w_qkv to bf16
    cast_bf16_kernel<<<192, 256, 0, stream>>>(w_qkv, wqkv_bf, 768 * 256 / 4);

    // 1) qkv = w_qkv @ x, q rows softmax'd in-epilogue; B (x) read once
    gemm_bstat<float, unsigned short, 6, true><<<dim3(256, 2), 512, 0, stream>>>(
        wqkv_bf, x, qkv_bf, 0L, 256L * NTOK, 768L * NTOK);

    // 2) context num/den via MFMA, fragments gathered straight from global
    ctx_mfma_kernel<<<dim3(NTOK / CCHUNK, 2), 512, 0, stream>>>(qkv_bf, num, den);

    // 3) W2 = fold(w_out, context) -> bf16
    combine_kernel<<<512, 256, 0, stream>>>(w_out, num, den, W2);

    // 4) out(fp32) = W2(bf16) @ q_soft(bf16); B (q_soft) read once
    gemm_bstat<unsigned short, float, 2, false><<<dim3(256, 2), 512, 0, stream>>>(
        W2, qkv_bf, out, 65536L, 768L * NTOK, 256L * NTOK);
}

// Round 3
// 296.170 us; speedup vs baseline: 1.0001x; 1.0001x over previous
//
#include <hip/hip_runtime.h>

#define NTOK 32768

typedef __attribute__((ext_vector_type(8))) short  bf16x8;
typedef __attribute__((ext_vector_type(8))) unsigned short u16x8;
typedef __attribute__((ext_vector_type(4))) float  f32x4;

__device__ __forceinline__ unsigned short f32_to_bf16(float f) {
    unsigned int u = __float_as_uint(f);
    u += 0x7FFFu + ((u >> 16) & 1u);          // round-to-nearest-even
    return (unsigned short)(u >> 16);
}
__device__ __forceinline__ float bf16_to_f32(unsigned short h) {
    return __uint_as_float(((unsigned int)h) << 16);
}

// ---------------------------------------------------------------------------
// B-stationary MFMA GEMM: C[M,NTOK] = A[M,256] * B[256,NTOK].
// One block per 128-col strip (x) per batch (y): B tile [256k][128n] staged
// to LDS bf16 transposed (Bs[n][k], 16B-granule XOR swizzle). 512 threads =
// 8 waves (4m x 2n): wave = 32 rows x 64 cols = 2mt x 4nt tiles.
// LDS (64KB) caps residency at 2 blocks/CU = 4 waves/EU; amdgpu_waves_per_eu
// is pinned to EXACTLY (4,4) so the allocator gets the full 128-VGPR budget.
// (Round-2 lesson: launch_bounds(512,4) let the compiler shrink to 64 VGPR
// and spill ~290MB/dispatch of scratch: FETCH 36->254MB, WRITE 96->172MB.)
// MFMA operands are SWAPPED (bf as A-operand): D lane layout becomes
// row=lane&15 (fixed), cols quad*4+r (consecutive) -> vectorized 8B/16B
// stores. A fragments gathered from global (L2-resident), no K-loop barriers.
// QSOFT: chunks 0,1 are q rows; each wave owns exactly one head's 32 rows ->
// softmax = mt-pair in-register + shfl_xor 1/2/4/8 over the m16 lanes.
// ---------------------------------------------------------------------------
template <typename BT, typename CT, int MCHUNKS, bool QSOFT>
__global__ __launch_bounds__(512)
__attribute__((amdgpu_waves_per_eu(4, 4)))
void gemm_bstat(
    const unsigned short* __restrict__ A, const BT* __restrict__ B,
    CT* __restrict__ C, long sA, long sB, long sC)
{
    const int bz = blockIdx.y;
    A += (long)bz * sA; B += (long)bz * sB; C += (long)bz * sC;
    const int col0 = blockIdx.x * 128;

    __shared__ unsigned short Bs[128 * 256];   // 64 KB

    const int t = threadIdx.x;
    const int wave = t >> 6, lane = t & 63;
    const int wm = wave >> 1, wn = wave & 1;   // 4 m-groups x 2 n-groups
    const int m16 = lane & 15, quad = lane >> 4;

    // ---- stage B tile once: [256k][128n] fp32/bf16 -> Bs[n][256k] bf16
    {
        const int n = t & 127;                  // column
        const int kg0 = (t >> 7) * 8;           // 4 k-quarters, 8 granules each
        const int key = n & 7;
        const BT* bcol = B + col0 + n;
        #pragma unroll
        for (int g = 0; g < 8; ++g) {
            const int kg = kg0 + g;             // 16B granule index along k (0..31)
            unsigned short tmp[8];
            #pragma unroll
            for (int i = 0; i < 8; ++i) {
                BT v = bcol[(size_t)(kg * 8 + i) * NTOK];
                if constexpr (sizeof(BT) == 4) tmp[i] = f32_to_bf16((float)v);
                else                           tmp[i] = (unsigned short)v;
            }
            *(u16x8*)&Bs[n * 256 + ((kg ^ key) * 8)] = *(const u16x8*)tmp;
        }
    }
    __syncthreads();   // the only barrier

    const int swk = m16 & 7;

    for (int mc = 0; mc < MCHUNKS; ++mc) {
        const int m0 = mc * 128;
        f32x4 acc[2][4] = {};

        // lane-base pointer into A for this chunk's fragments (32 rows/wave)
        const unsigned short* Abase = A + (size_t)(m0 + wm * 32 + m16) * 256 + quad * 8;

        #pragma unroll
        for (int kk = 0; kk < 8; ++kk) {
            bf16x8 bf[4];
            #pragma unroll
            for (int nt = 0; nt < 4; ++nt) {
                const int col = wn * 64 + nt * 16 + m16;
                bf[nt] = *(const bf16x8*)&Bs[col * 256 + (((kk * 4 + quad) ^ swk) * 8)];
            }
            #pragma unroll
            for (int mt = 0; mt < 2; ++mt) {
                const bf16x8 af = *(const bf16x8*)&Abase[(size_t)mt * 16 * 256 + kk * 32];
                #pragma unroll
                for (int nt = 0; nt < 4; ++nt)
                    acc[mt][nt] = __builtin_amdgcn_mfma_f32_16x16x32_bf16(
                        bf[nt], af, acc[mt][nt], 0, 0, 0);   // SWAPPED operands
            }
        }

        // ---- fused q softmax: wave owns one head's 32 rows (mt pair + m16 lanes)
        if (QSOFT && m0 < 256) {
            #pragma unroll
            for (int nt = 0; nt < 4; ++nt) {
                #pragma unroll
                for (int r = 0; r < 4; ++r) {
                    float mx = fmaxf(acc[0][nt][r], acc[1][nt][r]);
                    mx = fmaxf(mx, __shfl_xor(mx, 1, 64));
                    mx = fmaxf(mx, __shfl_xor(mx, 2, 64));
                    mx = fmaxf(mx, __shfl_xor(mx, 4, 64));
                    mx = fmaxf(mx, __shfl_xor(mx, 8, 64));
                    const float e0 = __expf(acc[0][nt][r] - mx);
                    const float e1 = __expf(acc[1][nt][r] - mx);
                    float s = e0 + e1;
                    s += __shfl_xor(s, 1, 64);
                    s += __shfl_xor(s, 2, 64);
                    s += __shfl_xor(s, 4, 64);
                    s += __shfl_xor(s, 8, 64);
                    const float inv = 1.0f / s;
                    acc[0][nt][r] = e0 * inv;
                    acc[1][nt][r] = e1 * inv;
                }
            }
        }

        // ---- store: lane holds row = mt*16+m16 (fixed), 4 consecutive cols
        #pragma unroll
        for (int mt = 0; mt < 2; ++mt) {
            const int row = m0 + wm * 32 + mt * 16 + m16;
            #pragma unroll
            for (int nt = 0; nt < 4; ++nt) {
                const int col = col0 + wn * 64 + nt * 16 + quad * 4;
                if constexpr (sizeof(CT) == 4) {
                    *(float4*)&C[(size_t)row * NTOK + col] =
                        *(const float4*)&acc[mt][nt];
                } else {
                    ushort4 o;
                    o.x = f32_to_bf16(acc[mt][nt][0]);
                    o.y = f32_to_bf16(acc[mt][nt][1]);
                    o.z = f32_to_bf16(acc[mt][nt][2]);
                    o.w = f32_to_bf16(acc[mt][nt][3]);
                    *(ushort4*)&C[(size_t)row * NTOK + col] = o;
                }
            }
        }
    }
}

// ---------------------------------------------------------------------------
// fp32 -> bf16 cast (vectorized)
// ---------------------------------------------------------------------------
__global__ __launch_bounds__(256) void cast_bf16_kernel(
    const float* __restrict__ src, unsigned short* __restrict__ dst, int n4)
{
    const int i = blockIdx.x * 256 + threadIdx.x;
    if (i < n4) {
        float4 v = ((const float4*)src)[i];
        ushort4 o;
        o.x = f32_to_bf16(v.x); o.y = f32_to_bf16(v.y);
        o.z = f32_to_bf16(v.z); o.w = f32_to_bf16(v.w);
        ((ushort4*)dst)[i] = o;
    }
}

// ---------------------------------------------------------------------------
// MFMA-based context: num[b,h,d,e] = sum_n exp(k[d,n]) * v[e,n];
// den[b,h,d] = sum_n exp(k[d,n]). Fragments gathered straight from global
// (tokens contiguous = MFMA K-dim -> 16B/lane loads). No LDS, no barriers.
// ---------------------------------------------------------------------------
#define CCHUNK 256
__global__ __launch_bounds__(512) void ctx_mfma_kernel(
    const unsigned short* __restrict__ qkv,
    float* __restrict__ num, float* __restrict__ den)
{
    const int b = blockIdx.y;
    const int n0 = blockIdx.x * CCHUNK;
    const int h = threadIdx.x >> 6;           // wave id == head id
    const int lane = threadIdx.x & 63;
    const int m16 = lane & 15, quad = lane >> 4;

    const unsigned short* kb =
        qkv + ((long)b * 768 + 256 + h * 32 + m16) * (long)NTOK + n0 + quad * 8;
    const unsigned short* vb =
        qkv + ((long)b * 768 + 512 + h * 32 + m16) * (long)NTOK + n0 + quad * 8;

    f32x4 acc[2][2] = {};       // [dtile][etile]
    float dp[2] = {0.f, 0.f};   // den partials

    #pragma unroll
    for (int n = 0; n < CCHUNK; n += 32) {
        bf16x8 af[2], bfv[2];
        #pragma unroll
        for (int dt = 0; dt < 2; ++dt) {
            const u16x8 kr = *(const u16x8*)(kb + (size_t)dt * 16 * NTOK + n);
            unsigned short tmp[8];
            #pragma unroll
            for (int i = 0; i < 8; ++i) {
                const float e = __expf(bf16_to_f32(kr[i]));
                const unsigned short eb = f32_to_bf16(e);
                tmp[i] = eb;
                dp[dt] += bf16_to_f32(eb);
            }
            af[dt] = *(const bf16x8*)tmp;
        }
        #pragma unroll
        for (int et = 0; et < 2; ++et)
            bfv[et] = *(const bf16x8*)(vb + (size_t)et * 16 * NTOK + n);
        #pragma unroll
        for (int dt = 0; dt < 2; ++dt)
            #pragma unroll
            for (int et = 0; et < 2; ++et)
                acc[dt][et] = __builtin_amdgcn_mfma_f32_16x16x32_bf16(
                    af[dt], bfv[et], acc[dt][et], 0, 0, 0);
    }

    float* nbase = num + ((long)(b * 8 + h) * 32) * 32;
    #pragma unroll
    for (int dt = 0; dt < 2; ++dt)
        #pragma unroll
        for (int et = 0; et < 2; ++et)
            #pragma unroll
            for (int r = 0; r < 4; ++r)
                atomicAdd(&nbase[(dt * 16 + quad * 4 + r) * 32 + et * 16 + m16],
                          acc[dt][et][r]);

    #pragma unroll
    for (int dt = 0; dt < 2; ++dt) {
        float s = dp[dt];
        s += __shfl_xor(s, 16, 64);
        s += __shfl_xor(s, 32, 64);
        if (quad == 0)
            atomicAdd(&den[b * 256 + h * 32 + dt * 16 + m16], s);
    }
}

// ---------------------------------------------------------------------------
// W2[b][o][h*32+d] = (sum_e w_out[o,h*32+e] * num[b,h,d,e]) / den[b,h*32+d]
// ---------------------------------------------------------------------------
__global__ __launch_bounds__(256) void combine_kernel(
    const float* __restrict__ w_out, const float* __restrict__ num,
    const float* __restrict__ den, unsigned short* __restrict__ W2)
{
    const int tid = blockIdx.x * 256 + threadIdx.x;   // 2*256*256 total
    const int b = tid >> 16;
    const int rem = tid & 65535;
    const int o = rem >> 8;
    const int i = rem & 255;
    const int h = i >> 5, d = i & 31;
    const float* wrow = w_out + o * 256 + h * 32;
    const float* nrow = num + (((long)(b * 8 + h) * 32 + d) << 5);
    float s = 0.f;
    #pragma unroll
    for (int e = 0; e < 32; ++e) s += wrow[e] * nrow[e];
    W2[tid] = f32_to_bf16(s / den[b * 256 + h * 32 + d]);
}

// ---------------------------------------------------------------------------
extern "C" void kernel_launch(void* const* d_in, const int* in_sizes, int n_in,
                              void* d_out, int out_size, void* d_ws, size_t ws_size,
                              hipStream_t stream)
{
    const float* x     = (const float*)d_in[0];   // [2,256,32768]
    const float* w_qkv = (const float*)d_in[1];   // [768,256]
    const float* w_out = (const float*)d_in[2];   // [256,256]
    float* out = (float*)d_out;                   // [2,256,32768]

    // workspace layout
    unsigned short* qkv_bf = (unsigned short*)d_ws;           // 2*768*32768 bf16
    const long qkv_elems = 2L * 768 * NTOK;
    unsigned short* wqkv_bf = qkv_bf + qkv_elems;             // 768*256 bf16
    unsigned short* W2 = wqkv_bf + 768 * 256;                 // 2*256*256 bf16
    float* num  = (float*)(W2 + 2 * 256 * 256);               // 16384
    float* den  = num + 16384;                                // 512

    hipMemsetAsync(num, 0, (16384 + 512) * sizeof(float), stream);

    // 0) cast w_qkv to bf16
    cast_bf16_kernel<<<192, 256, 0, stream>>>(w_qkv, wqkv_bf, 768 * 256 / 4);

    // 1) qkv = w_qkv @ x, q rows softmax'd in-epilogue; B (x) read once
    gemm_bstat<float, unsigned short, 6, true><<<dim3(256, 2), 512, 0, stream>>>(
        wqkv_bf, x, qkv_bf, 0L, 256L * NTOK, 768L * NTOK);

    // 2) context num/den via MFMA, fragments gathered straight from global
    ctx_mfma_kernel<<<dim3(NTOK / CCHUNK, 2), 512, 0, stream>>>(qkv_bf, num, den);

    // 3) W2 = fold(w_out, context) -> bf16
    combine_kernel<<<512, 256, 0, stream>>>(w_out, num, den, W2);

    // 4) out(fp32) = W2(bf16) @ q_soft(bf16); B (q_soft) read once
    gemm_bstat<unsigned short, float, 2, false><<<dim3(256, 2), 512, 0, stream>>>(
        W2, qkv_bf, out, 65536L, 768L * NTOK, 256L * NTOK);
}

// Round 5
// 287.424 us; speedup vs baseline: 1.0306x; 1.0304x over previous
//
#include <hip/hip_runtime.h>

#define NTOK 32768

typedef __attribute__((ext_vector_type(8))) short  bf16x8;
typedef __attribute__((ext_vector_type(8))) unsigned short u16x8;
typedef __attribute__((ext_vector_type(4))) float  f32x4;

__device__ __forceinline__ unsigned short f32_to_bf16(float f) {
    unsigned int u = __float_as_uint(f);
    u += 0x7FFFu + ((u >> 16) & 1u);          // round-to-nearest-even
    return (unsigned short)(u >> 16);
}
__device__ __forceinline__ float bf16_to_f32(unsigned short h) {
    return __uint_as_float(((unsigned int)h) << 16);
}

// ---------------------------------------------------------------------------
// B-stationary MFMA GEMM: C[M,NTOK] = A[M,256] * B[256,NTOK].
// One block per 64-col strip (x) per batch (y): B tile [256k][64n] staged to
// LDS bf16 transposed (Bs[n][k], 16B-granule XOR swizzle) = 32 KB -> 4-5
// blocks/CU. 256 threads = 4 waves (2m x 2n): wave = 64 rows x 32 cols =
// 4mt x 2nt tiles -> acc[4][2] = 32 VGPRs; natural allocation ~100 VGPR
// (4 waves/SIMD). NO launch-bounds min-occupancy / waves_per_eu pressure:
// rounds 2-3 proved 8-wave blocks + occupancy attributes make the allocator
// cap at 64 arch-VGPRs and spill ~290MB/dispatch of scratch.
// MFMA operands SWAPPED (bf as A-operand): D lane layout row=lane&15 (fixed),
// cols quad*4+r (consecutive) -> vectorized 8B/16B stores.
// A fragments gathered from global (L2-resident), no K-loop barriers.
// QSOFT: chunks 0,1 are q rows; wave rows = 2 heads (mt pairs 0-1, 2-3);
// softmax over a head's 32 rows = mt-pair in-register + shfl_xor 1/2/4/8.
// ---------------------------------------------------------------------------
template <typename BT, typename CT, int MCHUNKS, bool QSOFT>
__global__ __launch_bounds__(256) void gemm_bstat(
    const unsigned short* __restrict__ A, const BT* __restrict__ B,
    CT* __restrict__ C, long sA, long sB, long sC)
{
    const int bz = blockIdx.y;
    A += (long)bz * sA; B += (long)bz * sB; C += (long)bz * sC;
    const int col0 = blockIdx.x * 64;

    __shared__ unsigned short Bs[64 * 256];   // 32 KB

    const int t = threadIdx.x;
    const int wave = t >> 6, lane = t & 63;
    const int wm = wave >> 1, wn = wave & 1;   // 2 m-groups x 2 n-groups
    const int m16 = lane & 15, quad = lane >> 4;

    // ---- stage B tile once: [256k][64n] fp32/bf16 -> Bs[n][256k] bf16
    {
        const int n = t & 63;                   // column
        const int kg0 = (t >> 6) * 8;           // 4 k-quarters, 8 granules each
        const int key = n & 7;
        const BT* bcol = B + col0 + n;
        #pragma unroll
        for (int g = 0; g < 8; ++g) {
            const int kg = kg0 + g;             // 16B granule index along k (0..31)
            unsigned short tmp[8];
            #pragma unroll
            for (int i = 0; i < 8; ++i) {
                BT v = bcol[(size_t)(kg * 8 + i) * NTOK];
                if constexpr (sizeof(BT) == 4) tmp[i] = f32_to_bf16((float)v);
                else                           tmp[i] = (unsigned short)v;
            }
            *(u16x8*)&Bs[n * 256 + ((kg ^ key) * 8)] = *(const u16x8*)tmp;
        }
    }
    __syncthreads();   // the only barrier

    const int swk = m16 & 7;

    for (int mc = 0; mc < MCHUNKS; ++mc) {
        const int m0 = mc * 128;
        f32x4 acc[4][2] = {};

        // lane-base pointer into A for this chunk's fragments (64 rows/wave)
        const unsigned short* Abase = A + (size_t)(m0 + wm * 64 + m16) * 256 + quad * 8;

        #pragma unroll
        for (int kk = 0; kk < 8; ++kk) {
            bf16x8 bf[2];
            #pragma unroll
            for (int nt = 0; nt < 2; ++nt) {
                const int col = wn * 32 + nt * 16 + m16;
                bf[nt] = *(const bf16x8*)&Bs[col * 256 + (((kk * 4 + quad) ^ swk) * 8)];
            }
            #pragma unroll
            for (int mt = 0; mt < 4; ++mt) {
                const bf16x8 af = *(const bf16x8*)&Abase[(size_t)mt * 16 * 256 + kk * 32];
                #pragma unroll
                for (int nt = 0; nt < 2; ++nt)
                    acc[mt][nt] = __builtin_amdgcn_mfma_f32_16x16x32_bf16(
                        bf[nt], af, acc[mt][nt], 0, 0, 0);   // SWAPPED operands
            }
        }

        // ---- fused q softmax: mt pairs (0,1),(2,3) each = one head's 32 rows
        if (QSOFT && m0 < 256) {
            #pragma unroll
            for (int hj = 0; hj < 2; ++hj) {
                #pragma unroll
                for (int nt = 0; nt < 2; ++nt) {
                    #pragma unroll
                    for (int r = 0; r < 4; ++r) {
                        float mx = fmaxf(acc[hj * 2][nt][r], acc[hj * 2 + 1][nt][r]);
                        mx = fmaxf(mx, __shfl_xor(mx, 1, 64));
                        mx = fmaxf(mx, __shfl_xor(mx, 2, 64));
                        mx = fmaxf(mx, __shfl_xor(mx, 4, 64));
                        mx = fmaxf(mx, __shfl_xor(mx, 8, 64));
                        const float e0 = __expf(acc[hj * 2][nt][r] - mx);
                        const float e1 = __expf(acc[hj * 2 + 1][nt][r] - mx);
                        float s = e0 + e1;
                        s += __shfl_xor(s, 1, 64);
                        s += __shfl_xor(s, 2, 64);
                        s += __shfl_xor(s, 4, 64);
                        s += __shfl_xor(s, 8, 64);
                        const float inv = 1.0f / s;
                        acc[hj * 2][nt][r]     = e0 * inv;
                        acc[hj * 2 + 1][nt][r] = e1 * inv;
                    }
                }
            }
        }

        // ---- store: lane holds row = mt*16+m16 (fixed), 4 consecutive cols
        #pragma unroll
        for (int mt = 0; mt < 4; ++mt) {
            const int row = m0 + wm * 64 + mt * 16 + m16;
            #pragma unroll
            for (int nt = 0; nt < 2; ++nt) {
                const int col = col0 + wn * 32 + nt * 16 + quad * 4;
                if constexpr (sizeof(CT) == 4) {
                    *(float4*)&C[(size_t)row * NTOK + col] =
                        *(const float4*)&acc[mt][nt];
                } else {
                    ushort4 o;
                    o.x = f32_to_bf16(acc[mt][nt][0]);
                    o.y = f32_to_bf16(acc[mt][nt][1]);
                    o.z = f32_to_bf16(acc[mt][nt][2]);
                    o.w = f32_to_bf16(acc[mt][nt][3]);
                    *(ushort4*)&C[(size_t)row * NTOK + col] = o;
                }
            }
        }
    }
}

// ---------------------------------------------------------------------------
// fp32 -> bf16 cast (vectorized)
// ---------------------------------------------------------------------------
__global__ __launch_bounds__(256) void cast_bf16_kernel(
    const float* __restrict__ src, unsigned short* __restrict__ dst, int n4)
{
    const int i = blockIdx.x * 256 + threadIdx.x;
    if (i < n4) {
        float4 v = ((const float4*)src)[i];
        ushort4 o;
        o.x = f32_to_bf16(v.x); o.y = f32_to_bf16(v.y);
        o.z = f32_to_bf16(v.z); o.w = f32_to_bf16(v.w);
        ((ushort4*)dst)[i] = o;
    }
}

// ---------------------------------------------------------------------------
// MFMA-based context: num[b,h,d,e] = sum_n exp(k[d,n]) * v[e,n];
// den[b,h,d] = sum_n exp(k[d,n]). Fragments gathered straight from global
// (tokens contiguous = MFMA K-dim -> 16B/lane loads). No LDS, no barriers.
// ---------------------------------------------------------------------------
#define CCHUNK 256
__global__ __launch_bounds__(512) void ctx_mfma_kernel(
    const unsigned short* __restrict__ qkv,
    float* __restrict__ num, float* __restrict__ den)
{
    const int b = blockIdx.y;
    const int n0 = blockIdx.x * CCHUNK;
    const int h = threadIdx.x >> 6;           // wave id == head id
    const int lane = threadIdx.x & 63;
    const int m16 = lane & 15, quad = lane >> 4;

    const unsigned short* kb =
        qkv + ((long)b * 768 + 256 + h * 32 + m16) * (long)NTOK + n0 + quad * 8;
    const unsigned short* vb =
        qkv + ((long)b * 768 + 512 + h * 32 + m16) * (long)NTOK + n0 + quad * 8;

    f32x4 acc[2][2] = {};       // [dtile][etile]
    float dp[2] = {0.f, 0.f};   // den partials

    #pragma unroll
    for (int n = 0; n < CCHUNK; n += 32) {
        bf16x8 af[2], bfv[2];
        #pragma unroll
        for (int dt = 0; dt < 2; ++dt) {
            const u16x8 kr = *(const u16x8*)(kb + (size_t)dt * 16 * NTOK + n);
            unsigned short tmp[8];
            #pragma unroll
            for (int i = 0; i < 8; ++i) {
                const float e = __expf(bf16_to_f32(kr[i]));
                const unsigned short eb = f32_to_bf16(e);
                tmp[i] = eb;
                dp[dt] += bf16_to_f32(eb);
            }
            af[dt] = *(const bf16x8*)tmp;
        }
        #pragma unroll
        for (int et = 0; et < 2; ++et)
            bfv[et] = *(const bf16x8*)(vb + (size_t)et * 16 * NTOK + n);
        #pragma unroll
        for (int dt = 0; dt < 2; ++dt)
            #pragma unroll
            for (int et = 0; et < 2; ++et)
                acc[dt][et] = __builtin_amdgcn_mfma_f32_16x16x32_bf16(
                    af[dt], bfv[et], acc[dt][et], 0, 0, 0);
    }

    float* nbase = num + ((long)(b * 8 + h) * 32) * 32;
    #pragma unroll
    for (int dt = 0; dt < 2; ++dt)
        #pragma unroll
        for (int et = 0; et < 2; ++et)
            #pragma unroll
            for (int r = 0; r < 4; ++r)
                atomicAdd(&nbase[(dt * 16 + quad * 4 + r) * 32 + et * 16 + m16],
                          acc[dt][et][r]);

    #pragma unroll
    for (int dt = 0; dt < 2; ++dt) {
        float s = dp[dt];
        s += __shfl_xor(s, 16, 64);
        s += __shfl_xor(s, 32, 64);
        if (quad == 0)
            atomicAdd(&den[b * 256 + h * 32 + dt * 16 + m16], s);
    }
}

// ---------------------------------------------------------------------------
// W2[b][o][h*32+d] = (sum_e w_out[o,h*32+e] * num[b,h,d,e]) / den[b,h*32+d]
// ---------------------------------------------------------------------------
__global__ __launch_bounds__(256) void combine_kernel(
    const float* __restrict__ w_out, const float* __restrict__ num,
    const float* __restrict__ den, unsigned short* __restrict__ W2)
{
    const int tid = blockIdx.x * 256 + threadIdx.x;   // 2*256*256 total
    const int b = tid >> 16;
    const int rem = tid & 65535;
    const int o = rem >> 8;
    const int i = rem & 255;
    const int h = i >> 5, d = i & 31;
    const float* wrow = w_out + o * 256 + h * 32;
    const float* nrow = num + (((long)(b * 8 + h) * 32 + d) << 5);
    float s = 0.f;
    #pragma unroll
    for (int e = 0; e < 32; ++e) s += wrow[e] * nrow[e];
    W2[tid] = f32_to_bf16(s / den[b * 256 + h * 32 + d]);
}

// ---------------------------------------------------------------------------
extern "C" void kernel_launch(void* const* d_in, const int* in_sizes, int n_in,
                              void* d_out, int out_size, void* d_ws, size_t ws_size,
                              hipStream_t stream)
{
    const float* x     = (const float*)d_in[0];   // [2,256,32768]
    const float* w_qkv = (const float*)d_in[1];   // [768,256]
    const float* w_out = (const float*)d_in[2];   // [256,256]
    float* out = (float*)d_out;                   // [2,256,32768]

    // workspace layout
    unsigned short* qkv_bf = (unsigned short*)d_ws;           // 2*768*32768 bf16
    const long qkv_elems = 2L * 768 * NTOK;
    unsigned short* wqkv_bf = qkv_bf + qkv_elems;             // 768*256 bf16
    unsigned short* W2 = wqkv_bf + 768 * 256;                 // 2*256*256 bf16
    float* num  = (float*)(W2 + 2 * 256 * 256);               // 16384
    float* den  = num + 16384;                                // 512

    hipMemsetAsync(num, 0, (16384 + 512) * sizeof(float), stream);

    // 0) cast w_qkv to bf16
    cast_bf16_kernel<<<192, 256, 0, stream>>>(w_qkv, wqkv_bf, 768 * 256 / 4);

    // 1) qkv = w_qkv @ x, q rows softmax'd in-epilogue; B (x) read once
    gemm_bstat<float, unsigned short, 6, true><<<dim3(512, 2), 256, 0, stream>>>(
        wqkv_bf, x, qkv_bf, 0L, 256L * NTOK, 768L * NTOK);

    // 2) context num/den via MFMA, fragments gathered straight from global
    ctx_mfma_kernel<<<dim3(NTOK / CCHUNK, 2), 512, 0, stream>>>(qkv_bf, num, den);

    // 3) W2 = fold(w_out, context) -> bf16
    combine_kernel<<<512, 256, 0, stream>>>(w_out, num, den, W2);

    // 4) out(fp32) = W2(bf16) @ q_soft(bf16); B (q_soft) read once
    gemm_bstat<unsigned short, float, 2, false><<<dim3(512, 2), 256, 0, stream>>>(
        W2, qkv_bf, out, 65536L, 768L * NTOK, 256L * NTOK);
}

// Round 7
// 268.716 us; speedup vs baseline: 1.1023x; 1.0696x over previous
//
#include <hip/hip_runtime.h>

#define NTOK 32768

typedef __attribute__((ext_vector_type(8))) short  bf16x8;
typedef __attribute__((ext_vector_type(8))) unsigned short u16x8;
typedef __attribute__((ext_vector_type(4))) float  f32x4;

__device__ __forceinline__ unsigned short f32_to_bf16(float f) {
    unsigned int u = __float_as_uint(f);
    u += 0x7FFFu + ((u >> 16) & 1u);          // round-to-nearest-even
    return (unsigned short)(u >> 16);
}
__device__ __forceinline__ float bf16_to_f32(unsigned short h) {
    return __uint_as_float(((unsigned int)h) << 16);
}

// ---------------------------------------------------------------------------
// B-stationary MFMA GEMM: C[M,NTOK] = A[M,256] * B[256,NTOK].
// ROUND-1 PROVEN GEOMETRY (best measured): one block per 128-col strip (x)
// per batch (y); B tile [256k][128n] -> LDS bf16 transposed (Bs[n][k],
// 16B-granule XOR swizzle) = 64 KB -> 2 blocks/CU. 256 threads = 4 waves
// (2m x 2n): wave = 64 rows x 64 cols = 4mt x 4nt tiles, acc[4][4].
// Round-7 changes (contained dataflow only, no sync edits):
//  (a) SWAPPED MFMA operands (bf as A-operand; validated in round-5 pass):
//      D lane layout row(chan)=m16 fixed, cols(tok) quad*4+r consecutive ->
//      vectorized ushort4/float4 stores (96 insts/wave vs 384 scalar).
//  (b) 1-deep register prefetch of A-fragments: kk+1's 4 global loads issue
//      BEFORE kk's ds_reads + 16 MFMAs (~200cyc cover ~= L2 latency).
// A fragments gathered from global (L2-resident, 393KB), no K-loop barriers.
// QSOFT (round-5-validated form): chans = mt*16+m16; head = mt-pair; softmax
// reduce over m16 lanes via shfl_xor 1/2/4/8 per (nt,quad,r) token.
// ---------------------------------------------------------------------------
template <typename BT, typename CT, int MCHUNKS, bool QSOFT>
__global__ __launch_bounds__(256) void gemm_bstat(
    const unsigned short* __restrict__ A, const BT* __restrict__ B,
    CT* __restrict__ C, long sA, long sB, long sC)
{
    const int bz = blockIdx.y;
    A += (long)bz * sA; B += (long)bz * sB; C += (long)bz * sC;
    const int col0 = blockIdx.x * 128;

    __shared__ unsigned short Bs[128 * 256];   // 64 KB

    const int t = threadIdx.x;
    const int wave = t >> 6, lane = t & 63;
    const int wm = wave >> 1, wn = wave & 1;
    const int m16 = lane & 15, quad = lane >> 4;

    // ---- stage B tile once: [256k][128n] fp32/bf16 -> Bs[n][256k] bf16
    {
        const int n = t & 127;                  // waves 0,1 -> n 0..127, k-half 0
        const int kg0 = (t >> 7) * 16;          // waves 2,3 -> k-half 1
        const int key = n & 7;
        const BT* bcol = B + col0 + n;
        #pragma unroll
        for (int g = 0; g < 16; ++g) {
            const int kg = kg0 + g;             // 16B granule index along k (0..31)
            unsigned short tmp[8];
            #pragma unroll
            for (int i = 0; i < 8; ++i) {
                BT v = bcol[(size_t)(kg * 8 + i) * NTOK];
                if constexpr (sizeof(BT) == 4) tmp[i] = f32_to_bf16((float)v);
                else                           tmp[i] = (unsigned short)v;
            }
            *(u16x8*)&Bs[n * 256 + ((kg ^ key) * 8)] = *(const u16x8*)tmp;
        }
    }
    __syncthreads();   // the only barrier

    const int swk = m16 & 7;

    for (int mc = 0; mc < MCHUNKS; ++mc) {
        const int m0 = mc * 128;
        f32x4 acc[4][4] = {};

        // lane-base pointer into A for this chunk's fragments
        const unsigned short* Abase = A + (size_t)(m0 + wm * 64 + m16) * 256 + quad * 8;

        // prime the software pipeline: A fragments for kk=0
        bf16x8 af_cur[4], af_nxt[4];
        #pragma unroll
        for (int mt = 0; mt < 4; ++mt)
            af_cur[mt] = *(const bf16x8*)&Abase[(size_t)mt * 16 * 256];

        #pragma unroll
        for (int kk = 0; kk < 8; ++kk) {
            // (b) prefetch kk+1's A fragments FIRST: latency hides under the
            // ds_reads + 16 MFMAs below.
            if (kk < 7) {
                #pragma unroll
                for (int mt = 0; mt < 4; ++mt)
                    af_nxt[mt] = *(const bf16x8*)
                        &Abase[(size_t)mt * 16 * 256 + (kk + 1) * 32];
            }

            bf16x8 bf[4];
            #pragma unroll
            for (int nt = 0; nt < 4; ++nt) {
                const int col = wn * 64 + nt * 16 + m16;
                bf[nt] = *(const bf16x8*)&Bs[col * 256 + (((kk * 4 + quad) ^ swk) * 8)];
            }
            #pragma unroll
            for (int mt = 0; mt < 4; ++mt)
                #pragma unroll
                for (int nt = 0; nt < 4; ++nt)
                    acc[mt][nt] = __builtin_amdgcn_mfma_f32_16x16x32_bf16(
                        bf[nt], af_cur[mt], acc[mt][nt], 0, 0, 0);  // SWAPPED

            #pragma unroll
            for (int mt = 0; mt < 4; ++mt) af_cur[mt] = af_nxt[mt];
        }

        // ---- fused q softmax (round-5-validated): mt pairs (0,1),(2,3) are
        // heads; chan = mt*16+m16 -> reduce across the 16 m16 lanes.
        if (QSOFT && m0 < 256) {
            #pragma unroll
            for (int hj = 0; hj < 2; ++hj) {
                #pragma unroll
                for (int nt = 0; nt < 4; ++nt) {
                    #pragma unroll
                    for (int r = 0; r < 4; ++r) {
                        float mx = fmaxf(acc[hj * 2][nt][r], acc[hj * 2 + 1][nt][r]);
                        mx = fmaxf(mx, __shfl_xor(mx, 1, 64));
                        mx = fmaxf(mx, __shfl_xor(mx, 2, 64));
                        mx = fmaxf(mx, __shfl_xor(mx, 4, 64));
                        mx = fmaxf(mx, __shfl_xor(mx, 8, 64));
                        const float e0 = __expf(acc[hj * 2][nt][r] - mx);
                        const float e1 = __expf(acc[hj * 2 + 1][nt][r] - mx);
                        float s = e0 + e1;
                        s += __shfl_xor(s, 1, 64);
                        s += __shfl_xor(s, 2, 64);
                        s += __shfl_xor(s, 4, 64);
                        s += __shfl_xor(s, 8, 64);
                        const float inv = 1.0f / s;
                        acc[hj * 2][nt][r]     = e0 * inv;
                        acc[hj * 2 + 1][nt][r] = e1 * inv;
                    }
                }
            }
        }

        // ---- store: lane holds row(chan) = mt*16+m16, 4 consecutive cols
        #pragma unroll
        for (int mt = 0; mt < 4; ++mt) {
            const int row = m0 + wm * 64 + mt * 16 + m16;
            #pragma unroll
            for (int nt = 0; nt < 4; ++nt) {
                const int col = col0 + wn * 64 + nt * 16 + quad * 4;
                if constexpr (sizeof(CT) == 4) {
                    *(float4*)&C[(size_t)row * NTOK + col] =
                        *(const float4*)&acc[mt][nt];
                } else {
                    ushort4 o;
                    o.x = f32_to_bf16(acc[mt][nt][0]);
                    o.y = f32_to_bf16(acc[mt][nt][1]);
                    o.z = f32_to_bf16(acc[mt][nt][2]);
                    o.w = f32_to_bf16(acc[mt][nt][3]);
                    *(ushort4*)&C[(size_t)row * NTOK + col] = o;
                }
            }
        }
    }
}

// ---------------------------------------------------------------------------
// fp32 -> bf16 cast (vectorized)
// ---------------------------------------------------------------------------
__global__ __launch_bounds__(256) void cast_bf16_kernel(
    const float* __restrict__ src, unsigned short* __restrict__ dst, int n4)
{
    const int i = blockIdx.x * 256 + threadIdx.x;
    if (i < n4) {
        float4 v = ((const float4*)src)[i];
        ushort4 o;
        o.x = f32_to_bf16(v.x); o.y = f32_to_bf16(v.y);
        o.z = f32_to_bf16(v.z); o.w = f32_to_bf16(v.w);
        ((ushort4*)dst)[i] = o;
    }
}

// ---------------------------------------------------------------------------
// MFMA-based context: num[b,h,d,e] = sum_n exp(k[d,n]) * v[e,n];
// den[b,h,d] = sum_n exp(k[d,n]). Fragments gathered straight from global
// (tokens contiguous = MFMA K-dim -> 16B/lane loads). No LDS, no barriers.
// ---------------------------------------------------------------------------
#define CCHUNK 256
__global__ __launch_bounds__(512) void ctx_mfma_kernel(
    const unsigned short* __restrict__ qkv,
    float* __restrict__ num, float* __restrict__ den)
{
    const int b = blockIdx.y;
    const int n0 = blockIdx.x * CCHUNK;
    const int h = threadIdx.x >> 6;           // wave id == head id
    const int lane = threadIdx.x & 63;
    const int m16 = lane & 15, quad = lane >> 4;

    const unsigned short* kb =
        qkv + ((long)b * 768 + 256 + h * 32 + m16) * (long)NTOK + n0 + quad * 8;
    const unsigned short* vb =
        qkv + ((long)b * 768 + 512 + h * 32 + m16) * (long)NTOK + n0 + quad * 8;

    f32x4 acc[2][2] = {};       // [dtile][etile]
    float dp[2] = {0.f, 0.f};   // den partials

    #pragma unroll
    for (int n = 0; n < CCHUNK; n += 32) {
        bf16x8 af[2], bfv[2];
        #pragma unroll
        for (int dt = 0; dt < 2; ++dt) {
            const u16x8 kr = *(const u16x8*)(kb + (size_t)dt * 16 * NTOK + n);
            unsigned short tmp[8];
            #pragma unroll
            for (int i = 0; i < 8; ++i) {
                const float e = __expf(bf16_to_f32(kr[i]));
                const unsigned short eb = f32_to_bf16(e);
                tmp[i] = eb;
                dp[dt] += bf16_to_f32(eb);
            }
            af[dt] = *(const bf16x8*)tmp;
        }
        #pragma unroll
        for (int et = 0; et < 2; ++et)
            bfv[et] = *(const bf16x8*)(vb + (size_t)et * 16 * NTOK + n);
        #pragma unroll
        for (int dt = 0; dt < 2; ++dt)
            #pragma unroll
            for (int et = 0; et < 2; ++et)
                acc[dt][et] = __builtin_amdgcn_mfma_f32_16x16x32_bf16(
                    af[dt], bfv[et], acc[dt][et], 0, 0, 0);
    }

    float* nbase = num + ((long)(b * 8 + h) * 32) * 32;
    #pragma unroll
    for (int dt = 0; dt < 2; ++dt)
        #pragma unroll
        for (int et = 0; et < 2; ++et)
            #pragma unroll
            for (int r = 0; r < 4; ++r)
                atomicAdd(&nbase[(dt * 16 + quad * 4 + r) * 32 + et * 16 + m16],
                          acc[dt][et][r]);

    #pragma unroll
    for (int dt = 0; dt < 2; ++dt) {
        float s = dp[dt];
        s += __shfl_xor(s, 16, 64);
        s += __shfl_xor(s, 32, 64);
        if (quad == 0)
            atomicAdd(&den[b * 256 + h * 32 + dt * 16 + m16], s);
    }
}

// ---------------------------------------------------------------------------
// W2[b][o][h*32+d] = (sum_e w_out[o,h*32+e] * num[b,h,d,e]) / den[b,h*32+d]
// ---------------------------------------------------------------------------
__global__ __launch_bounds__(256) void combine_kernel(
    const float* __restrict__ w_out, const float* __restrict__ num,
    const float* __restrict__ den, unsigned short* __restrict__ W2)
{
    const int tid = blockIdx.x * 256 + threadIdx.x;   // 2*256*256 total
    const int b = tid >> 16;
    const int rem = tid & 65535;
    const int o = rem >> 8;
    const int i = rem & 255;
    const int h = i >> 5, d = i & 31;
    const float* wrow = w_out + o * 256 + h * 32;
    const float* nrow = num + (((long)(b * 8 + h) * 32 + d) << 5);
    float s = 0.f;
    #pragma unroll
    for (int e = 0; e < 32; ++e) s += wrow[e] * nrow[e];
    W2[tid] = f32_to_bf16(s / den[b * 256 + h * 32 + d]);
}

// ---------------------------------------------------------------------------
extern "C" void kernel_launch(void* const* d_in, const int* in_sizes, int n_in,
                              void* d_out, int out_size, void* d_ws, size_t ws_size,
                              hipStream_t stream)
{
    const float* x     = (const float*)d_in[0];   // [2,256,32768]
    const float* w_qkv = (const float*)d_in[1];   // [768,256]
    const float* w_out = (const float*)d_in[2];   // [256,256]
    float* out = (float*)d_out;                   // [2,256,32768]

    // workspace layout
    unsigned short* qkv_bf = (unsigned short*)d_ws;           // 2*768*32768 bf16
    const long qkv_elems = 2L * 768 * NTOK;
    unsigned short* wqkv_bf = qkv_bf + qkv_elems;             // 768*256 bf16
    unsigned short* W2 = wqkv_bf + 768 * 256;                 // 2*256*256 bf16
    float* num  = (float*)(W2 + 2 * 256 * 256);               // 16384
    float* den  = num + 16384;                                // 512

    hipMemsetAsync(num, 0, (16384 + 512) * sizeof(float), stream);

    // 0) cast w_qkv to bf16
    cast_bf16_kernel<<<192, 256, 0, stream>>>(w_qkv, wqkv_bf, 768 * 256 / 4);

    // 1) qkv = w_qkv @ x, q rows softmax'd in-epilogue; B (x) read once
    gemm_bstat<float, unsigned short, 6, true><<<dim3(256, 2), 256, 0, stream>>>(
        wqkv_bf, x, qkv_bf, 0L, 256L * NTOK, 768L * NTOK);

    // 2) context num/den via MFMA, fragments gathered straight from global
    ctx_mfma_kernel<<<dim3(NTOK / CCHUNK, 2), 512, 0, stream>>>(qkv_bf, num, den);

    // 3) W2 = fold(w_out, context) -> bf16
    combine_kernel<<<512, 256, 0, stream>>>(w_out, num, den, W2);

    // 4) out(fp32) = W2(bf16) @ q_soft(bf16); B (q_soft) read once
    gemm_bstat<unsigned short, float, 2, false><<<dim3(256, 2), 256, 0, stream>>>(
        W2, qkv_bf, out, 65536L, 768L * NTOK, 256L * NTOK);
}

// Round 8
// 267.808 us; speedup vs baseline: 1.1060x; 1.0034x over previous
//
#include <hip/hip_runtime.h>

#define NTOK 32768
#define TSTRIP 98304   // 768 chans * 128 toks per qkv strip-tile

typedef __attribute__((ext_vector_type(8))) short  bf16x8;
typedef __attribute__((ext_vector_type(8))) unsigned short u16x8;
typedef __attribute__((ext_vector_type(4))) float  f32x4;

__device__ __forceinline__ unsigned short f32_to_bf16(float f) {
    unsigned int u = __float_as_uint(f);
    u += 0x7FFFu + ((u >> 16) & 1u);          // round-to-nearest-even
    return (unsigned short)(u >> 16);
}
__device__ __forceinline__ float bf16_to_f32(unsigned short h) {
    return __uint_as_float(((unsigned int)h) << 16);
}

// ---------------------------------------------------------------------------
// B-stationary MFMA GEMM: C[M,NTOK] = A[M,256] * B[256,NTOK].
// Geometry: round-1 proven (128-col strip/block, 64KB Bs, 4 waves 64x64).
// ROUND-8: STRIP-TILED qkv layout qkv_t[strip][768][128].
// Rounds 1/5/7 all pinned at 126-136us with every pipe idle and ~134MB at
// ~1.05TB/s -> scattered-granule memory wall (256B-at-128KB-stride reads,
// 32B-segment scattered writes). Tiled layout makes gemm1's C-write one
// contiguous 192KB stream per block and gemm2's B-tile one contiguous 64KB
// read. BTILED/CTILED select flat (x / out, fixed layouts) vs tiled bases.
// MFMA operands SWAPPED (bf as A-operand) -> lane row(chan)=m16 fixed, cols
// quad*4+r consecutive -> ushort4/float4 stores. A-fragments from global
// (L2-resident) with 1-deep register prefetch. QSOFT: softmax over m16 lanes.
// ---------------------------------------------------------------------------
template <typename BT, typename CT, int MCHUNKS, bool QSOFT, bool BTILED, bool CTILED>
__global__ __launch_bounds__(256) void gemm_bstat(
    const unsigned short* __restrict__ A, const BT* __restrict__ B,
    CT* __restrict__ C, long sA, long sB, long sC)
{
    const int bz = blockIdx.y;
    A += (long)bz * sA; B += (long)bz * sB; C += (long)bz * sC;
    const int strip = blockIdx.x;
    const int col0 = strip * 128;

    // B base + token-stride: tiled -> strip tile, rows are 128 long
    const BT* Bbase = BTILED ? B + (size_t)strip * TSTRIP : B + col0;
    const long bstride = BTILED ? 128 : NTOK;
    // C base + row-stride
    CT* Cbase = CTILED ? C + (size_t)strip * TSTRIP : C + col0;
    const long cstride = CTILED ? 128 : NTOK;

    __shared__ unsigned short Bs[128 * 256];   // 64 KB

    const int t = threadIdx.x;
    const int wave = t >> 6, lane = t & 63;
    const int wm = wave >> 1, wn = wave & 1;
    const int m16 = lane & 15, quad = lane >> 4;

    // ---- stage B tile once: [256k][128n] -> Bs[n][256k] bf16 (XOR swizzle)
    {
        const int n = t & 127;                  // waves 0,1 -> k-half 0
        const int kg0 = (t >> 7) * 16;          // waves 2,3 -> k-half 1
        const int key = n & 7;
        const BT* bcol = Bbase + n;
        #pragma unroll
        for (int g = 0; g < 16; ++g) {
            const int kg = kg0 + g;             // 16B granule index along k (0..31)
            unsigned short tmp[8];
            #pragma unroll
            for (int i = 0; i < 8; ++i) {
                BT v = bcol[(size_t)(kg * 8 + i) * bstride];
                if constexpr (sizeof(BT) == 4) tmp[i] = f32_to_bf16((float)v);
                else                           tmp[i] = (unsigned short)v;
            }
            *(u16x8*)&Bs[n * 256 + ((kg ^ key) * 8)] = *(const u16x8*)tmp;
        }
    }
    __syncthreads();   // the only barrier

    const int swk = m16 & 7;

    for (int mc = 0; mc < MCHUNKS; ++mc) {
        const int m0 = mc * 128;
        f32x4 acc[4][4] = {};

        const unsigned short* Abase = A + (size_t)(m0 + wm * 64 + m16) * 256 + quad * 8;

        bf16x8 af_cur[4], af_nxt[4];
        #pragma unroll
        for (int mt = 0; mt < 4; ++mt)
            af_cur[mt] = *(const bf16x8*)&Abase[(size_t)mt * 16 * 256];

        #pragma unroll
        for (int kk = 0; kk < 8; ++kk) {
            if (kk < 7) {
                #pragma unroll
                for (int mt = 0; mt < 4; ++mt)
                    af_nxt[mt] = *(const bf16x8*)
                        &Abase[(size_t)mt * 16 * 256 + (kk + 1) * 32];
            }

            bf16x8 bf[4];
            #pragma unroll
            for (int nt = 0; nt < 4; ++nt) {
                const int col = wn * 64 + nt * 16 + m16;
                bf[nt] = *(const bf16x8*)&Bs[col * 256 + (((kk * 4 + quad) ^ swk) * 8)];
            }
            #pragma unroll
            for (int mt = 0; mt < 4; ++mt)
                #pragma unroll
                for (int nt = 0; nt < 4; ++nt)
                    acc[mt][nt] = __builtin_amdgcn_mfma_f32_16x16x32_bf16(
                        bf[nt], af_cur[mt], acc[mt][nt], 0, 0, 0);  // SWAPPED

            #pragma unroll
            for (int mt = 0; mt < 4; ++mt) af_cur[mt] = af_nxt[mt];
        }

        // ---- fused q softmax: mt pairs (0,1),(2,3) are heads; chan=mt*16+m16
        if (QSOFT && m0 < 256) {
            #pragma unroll
            for (int hj = 0; hj < 2; ++hj) {
                #pragma unroll
                for (int nt = 0; nt < 4; ++nt) {
                    #pragma unroll
                    for (int r = 0; r < 4; ++r) {
                        float mx = fmaxf(acc[hj * 2][nt][r], acc[hj * 2 + 1][nt][r]);
                        mx = fmaxf(mx, __shfl_xor(mx, 1, 64));
                        mx = fmaxf(mx, __shfl_xor(mx, 2, 64));
                        mx = fmaxf(mx, __shfl_xor(mx, 4, 64));
                        mx = fmaxf(mx, __shfl_xor(mx, 8, 64));
                        const float e0 = __expf(acc[hj * 2][nt][r] - mx);
                        const float e1 = __expf(acc[hj * 2 + 1][nt][r] - mx);
                        float s = e0 + e1;
                        s += __shfl_xor(s, 1, 64);
                        s += __shfl_xor(s, 2, 64);
                        s += __shfl_xor(s, 4, 64);
                        s += __shfl_xor(s, 8, 64);
                        const float inv = 1.0f / s;
                        acc[hj * 2][nt][r]     = e0 * inv;
                        acc[hj * 2 + 1][nt][r] = e1 * inv;
                    }
                }
            }
        }

        // ---- store: lane holds row(chan)=mt*16+m16, 4 consecutive local cols
        #pragma unroll
        for (int mt = 0; mt < 4; ++mt) {
            const int row = m0 + wm * 64 + mt * 16 + m16;
            #pragma unroll
            for (int nt = 0; nt < 4; ++nt) {
                const int col = wn * 64 + nt * 16 + quad * 4;   // local 0..127
                if constexpr (sizeof(CT) == 4) {
                    *(float4*)&Cbase[(size_t)row * cstride + col] =
                        *(const float4*)&acc[mt][nt];
                } else {
                    ushort4 o;
                    o.x = f32_to_bf16(acc[mt][nt][0]);
                    o.y = f32_to_bf16(acc[mt][nt][1]);
                    o.z = f32_to_bf16(acc[mt][nt][2]);
                    o.w = f32_to_bf16(acc[mt][nt][3]);
                    *(ushort4*)&Cbase[(size_t)row * cstride + col] = o;
                }
            }
        }
    }
}

// ---------------------------------------------------------------------------
// fp32 -> bf16 cast (vectorized)
// ---------------------------------------------------------------------------
__global__ __launch_bounds__(256) void cast_bf16_kernel(
    const float* __restrict__ src, unsigned short* __restrict__ dst, int n4)
{
    const int i = blockIdx.x * 256 + threadIdx.x;
    if (i < n4) {
        float4 v = ((const float4*)src)[i];
        ushort4 o;
        o.x = f32_to_bf16(v.x); o.y = f32_to_bf16(v.y);
        o.z = f32_to_bf16(v.z); o.w = f32_to_bf16(v.w);
        ((ushort4*)dst)[i] = o;
    }
}

// ---------------------------------------------------------------------------
// MFMA-based context on the STRIP-TILED qkv: num[b,h,d,e] += exp(k)*v.
// Block covers 2 strips (256 toks); within a strip, chan rows are 128-tok
// contiguous -> fragment loads are 16B contiguous within an 8KB window.
// ---------------------------------------------------------------------------
__global__ __launch_bounds__(512) void ctx_mfma_kernel(
    const unsigned short* __restrict__ qkv,
    float* __restrict__ num, float* __restrict__ den)
{
    const int b = blockIdx.y;
    const int s0 = blockIdx.x * 2;            // 2 strips per block
    const int h = threadIdx.x >> 6;           // wave id == head id
    const int lane = threadIdx.x & 63;
    const int m16 = lane & 15, quad = lane >> 4;

    const unsigned short* base = qkv + (long)b * 768 * NTOK;

    f32x4 acc[2][2] = {};       // [dtile][etile]
    float dp[2] = {0.f, 0.f};   // den partials

    #pragma unroll
    for (int st = 0; st < 2; ++st) {
        const unsigned short* tile = base + (size_t)(s0 + st) * TSTRIP;
        const unsigned short* kp = tile + (256 + h * 32 + m16) * 128 + quad * 8;
        const unsigned short* vp = tile + (512 + h * 32 + m16) * 128 + quad * 8;
        #pragma unroll
        for (int kg = 0; kg < 4; ++kg) {
            const int off = kg * 32;
            bf16x8 af[2], bfv[2];
            #pragma unroll
            for (int dt = 0; dt < 2; ++dt) {
                const u16x8 kr = *(const u16x8*)(kp + dt * 2048 + off);
                unsigned short tmp[8];
                #pragma unroll
                for (int i = 0; i < 8; ++i) {
                    const float e = __expf(bf16_to_f32(kr[i]));
                    const unsigned short eb = f32_to_bf16(e);
                    tmp[i] = eb;
                    dp[dt] += bf16_to_f32(eb);
                }
                af[dt] = *(const bf16x8*)tmp;
            }
            #pragma unroll
            for (int et = 0; et < 2; ++et)
                bfv[et] = *(const bf16x8*)(vp + et * 2048 + off);
            #pragma unroll
            for (int dt = 0; dt < 2; ++dt)
                #pragma unroll
                for (int et = 0; et < 2; ++et)
                    acc[dt][et] = __builtin_amdgcn_mfma_f32_16x16x32_bf16(
                        af[dt], bfv[et], acc[dt][et], 0, 0, 0);
        }
    }

    float* nbase = num + ((long)(b * 8 + h) * 32) * 32;
    #pragma unroll
    for (int dt = 0; dt < 2; ++dt)
        #pragma unroll
        for (int et = 0; et < 2; ++et)
            #pragma unroll
            for (int r = 0; r < 4; ++r)
                atomicAdd(&nbase[(dt * 16 + quad * 4 + r) * 32 + et * 16 + m16],
                          acc[dt][et][r]);

    #pragma unroll
    for (int dt = 0; dt < 2; ++dt) {
        float s = dp[dt];
        s += __shfl_xor(s, 16, 64);
        s += __shfl_xor(s, 32, 64);
        if (quad == 0)
            atomicAdd(&den[b * 256 + h * 32 + dt * 16 + m16], s);
    }
}

// ---------------------------------------------------------------------------
// W2[b][o][h*32+d] = (sum_e w_out[o,h*32+e] * num[b,h,d,e]) / den[b,h*32+d]
// ---------------------------------------------------------------------------
__global__ __launch_bounds__(256) void combine_kernel(
    const float* __restrict__ w_out, const float* __restrict__ num,
    const float* __restrict__ den, unsigned short* __restrict__ W2)
{
    const int tid = blockIdx.x * 256 + threadIdx.x;   // 2*256*256 total
    const int b = tid >> 16;
    const int rem = tid & 65535;
    const int o = rem >> 8;
    const int i = rem & 255;
    const int h = i >> 5, d = i & 31;
    const float* wrow = w_out + o * 256 + h * 32;
    const float* nrow = num + (((long)(b * 8 + h) * 32 + d) << 5);
    float s = 0.f;
    #pragma unroll
    for (int e = 0; e < 32; ++e) s += wrow[e] * nrow[e];
    W2[tid] = f32_to_bf16(s / den[b * 256 + h * 32 + d]);
}

// ---------------------------------------------------------------------------
extern "C" void kernel_launch(void* const* d_in, const int* in_sizes, int n_in,
                              void* d_out, int out_size, void* d_ws, size_t ws_size,
                              hipStream_t stream)
{
    const float* x     = (const float*)d_in[0];   // [2,256,32768]
    const float* w_qkv = (const float*)d_in[1];   // [768,256]
    const float* w_out = (const float*)d_in[2];   // [256,256]
    float* out = (float*)d_out;                   // [2,256,32768]

    // workspace layout (qkv now strip-tiled: [b][strip][768][128] bf16)
    unsigned short* qkv_bf = (unsigned short*)d_ws;           // 2*768*32768 bf16
    const long qkv_elems = 2L * 768 * NTOK;
    unsigned short* wqkv_bf = qkv_bf + qkv_elems;             // 768*256 bf16
    unsigned short* W2 = wqkv_bf + 768 * 256;                 // 2*256*256 bf16
    float* num  = (float*)(W2 + 2 * 256 * 256);               // 16384
    float* den  = num + 16384;                                // 512

    hipMemsetAsync(num, 0, (16384 + 512) * sizeof(float), stream);

    // 0) cast w_qkv to bf16
    cast_bf16_kernel<<<192, 256, 0, stream>>>(w_qkv, wqkv_bf, 768 * 256 / 4);

    // 1) qkv_t = w_qkv @ x (B flat x, C strip-tiled); q softmax'd in-epilogue
    gemm_bstat<float, unsigned short, 6, true, false, true>
        <<<dim3(256, 2), 256, 0, stream>>>(
        wqkv_bf, x, qkv_bf, 0L, 256L * NTOK, 768L * NTOK);

    // 2) context num/den via MFMA on tiled qkv
    ctx_mfma_kernel<<<dim3(NTOK / 256, 2), 512, 0, stream>>>(qkv_bf, num, den);

    // 3) W2 = fold(w_out, context) -> bf16
    combine_kernel<<<512, 256, 0, stream>>>(w_out, num, den, W2);

    // 4) out = W2 @ q_soft (B strip-tiled, C flat fp32)
    gemm_bstat<unsigned short, float, 2, false, true, false>
        <<<dim3(256, 2), 256, 0, stream>>>(
        W2, qkv_bf, out, 65536L, 768L * NTOK, 256L * NTOK);
}